// Round 11
// baseline (792.463 us; speedup 1.0000x reference)
//
#include <hip/hip_runtime.h>

// Heat equation, 2 materials, N=512, 499 steps, all frames written.
// R11: ONE persistent kernel (grid 256 = #CUs, 1024 thr/block), R9's
// intra-block engine (1x4 strips, DPP left/right, nearest-neighbor wave
// flags in LDS, async frame stores). Kernel launches are replaced by
// super-step boundaries every 16 steps: vmcnt drain + threadfence +
// device-scope flag, spin on 8 neighbor blocks' flags, acquire fence,
// re-stage halo ring from the last written frame (owned tile stays in
// registers). Flags in d_ws, zeroed per call via hipMemsetAsync.

#define GN 512
#define NSTEPS 499
#define MBND 256
#define INV_DX2 261121.0f     // 511^2 = 1/dx^2
#define DT 5e-7f

#define TO 32                 // owned tile edge
#define KMAX 16               // steps per super-step (= trapezoid margin)
#define LOAD 64               // TO + 2*KMAX
#define LSTR 68               // padded LDS row stride (floats)
#define NSUP 31               // 31*16 = 496, tail = 3
#define PTS (GN * GN)

// DPP shifts within 16-lane rows (= one ty row of threads). Out-of-range
// lanes keep their own value (bound_ctrl=0, old=src) -> junk only at
// region edges, outside the validity trapezoid.
__device__ __forceinline__ float dpp_row_shr1(float x) {  // lane i <- i-1
    int v = __builtin_amdgcn_update_dpp(__float_as_int(x), __float_as_int(x),
                                        0x111, 0xf, 0xf, false);
    return __int_as_float(v);
}
__device__ __forceinline__ float dpp_row_shl1(float x) {  // lane i <- i+1
    int v = __builtin_amdgcn_update_dpp(__float_as_int(x), __float_as_int(x),
                                        0x101, 0xf, 0xf, false);
    return __int_as_float(v);
}

struct Prm {
    float Ac[4]; bool ifc[4]; bool bcl[4];
    float k1, k2, invk;
    bool aI, aC, aR;
};

__device__ __forceinline__ void srow(const float x[4], const float up[4],
                                     const float dn[4], float out[4],
                                     const Prm& p, bool brF)
{
    const float lf = dpp_row_shr1(x[3]);
    const float rg = dpp_row_shl1(x[0]);
    const float le[4] = {lf, x[0], x[1], x[2]};
    const float ri[4] = {x[1], x[2], x[3], rg};
    #pragma unroll
    for (int j = 0; j < 4; ++j) {
        float v = fmaf(p.Ac[j], fmaf(-4.0f, x[j], (up[j] + dn[j]) + (le[j] + ri[j])), x[j]);
        if (p.aI) v = p.ifc[j] ? (p.k1 * ri[j] + p.k2 * le[j]) * p.invk : v; // OLD nbrs
        if (p.aC) v = p.bcl[j] ? 0.0f : v;
        if (p.aR) v = brF ? 0.0f : v;
        out[j] = v;
    }
}

__device__ __forceinline__ void ld4(float d[4], const float* s) {
    const float4 v = *(const float4*)s;
    d[0] = v.x; d[1] = v.y; d[2] = v.z; d[3] = v.w;
}

__global__ __launch_bounds__(1024) void heat_pers(
    const float* __restrict__ Tin, float* __restrict__ outBase,
    const float* __restrict__ k1p, const float* __restrict__ k2p,
    const float* __restrict__ a1p, const float* __restrict__ a2p,
    int* __restrict__ gfl)
{
    __shared__ float Sb[2][LOAD][LSTR];
    __shared__ int fl[16];

    const int t  = threadIdx.x;              // 0..1023
    const int bid = blockIdx.x;
    const int bi = bid >> 4;                 // 16x16 tile grid
    const int bj = bid & 15;
    const int gi0 = bi * TO - KMAX;
    const int gj0 = bj * TO - KMAX;

    const int tx = t & 15, ty = t >> 4;      // 64 rows x 16 col-groups
    const int w  = t >> 6;                   // wave id 0..15
    const int lj0 = tx * 4;

    // 8-neighbor block ids for lanes t<8 (-1 = none)
    int nbid = -1;
    if (t < 8) {
        const int idx = (t < 4) ? t : t + 1;           // skip center
        const int di = idx / 3 - 1, dj = idx % 3 - 1;
        const int nbi = bi + di, nbj = bj + dj;
        if ((unsigned)nbi < 16u && (unsigned)nbj < 16u) nbid = nbi * 16 + nbj;
    }

    // ---- stage region @t0 from u0
    float C[4];
    {
        const bool innerB = (gi0 >= 0) && (gi0 + LOAD <= GN) &&
                            (gj0 >= 0) && (gj0 + LOAD <= GN);
        float4 v;
        if (innerB) {
            v = *(const float4*)&Tin[(size_t)(gi0 + ty) * GN + (gj0 + lj0)];
        } else {
            const int gi_ = gi0 + ty;
            float tmp[4];
            #pragma unroll
            for (int e = 0; e < 4; ++e) {
                const int gj_ = gj0 + lj0 + e;
                tmp[e] = ((unsigned)gi_ < GN && (unsigned)gj_ < GN)
                         ? Tin[(size_t)gi_ * GN + gj_] : 0.0f;
            }
            v = make_float4(tmp[0], tmp[1], tmp[2], tmp[3]);
        }
        *(float4*)&Sb[0][ty][lj0] = v;
        C[0] = v.x; C[1] = v.y; C[2] = v.z; C[3] = v.w;
    }
    if (t < 16) fl[t] = 0;
    __syncthreads();

    const int rm1 = (ty >= 1) ? ty - 1 : 0;
    const int rp1 = (ty <= LOAD - 2) ? ty + 1 : LOAD - 1;
    const int wm1 = (w == 0) ? 0 : w - 1;
    const int wp1 = (w == 15) ? 15 : w + 1;

    Prm p;
    p.k1 = k1p[0]; p.k2 = k2p[0];
    const float a1 = a1p[0], a2 = a2p[0];
    p.invk = 1.0f / (p.k1 + p.k2);
    #pragma unroll
    for (int j = 0; j < 4; ++j) {
        const int gj_ = gj0 + lj0 + j;
        p.Ac[j]  = (DT * INV_DX2) * ((gj_ < MBND) ? a1 : a2);
        p.ifc[j] = (gj_ == MBND - 1);
        p.bcl[j] = (gj_ <= 0) || (gj_ >= GN - 1);
    }
    p.aI = (bj == 7) || (bj == 8);
    p.aC = (bj == 0) || (bj == 15);
    p.aR = (bi == 0) || (bi == 15);

    const int gi = gi0 + ty;
    const bool br0 = (gi <= 0) || (gi >= GN - 1);
    const bool own = (tx >= 4) && (tx < 12) && (ty >= KMAX) && (ty < KMAX + TO);
    float* dst = outBase + ((long)gi * GN + (gj0 + lj0));

    #pragma unroll 1
    for (int sup = 0; sup < NSUP; ++sup) {
        const int sbase = sup * KMAX;
        #pragma unroll
        for (int q = 1; q <= KMAX; ++q) {
            const int s = sbase + q;
            if (q > 1) {   // q==1 covered by boundary/initial __syncthreads
                while (__atomic_load_n(&fl[wm1], __ATOMIC_ACQUIRE) < s - 1 ||
                       __atomic_load_n(&fl[wp1], __ATOMIC_ACQUIRE) < s - 1)
                    __builtin_amdgcn_s_sleep(1);
            }
            const float (*Rb)[LSTR] = Sb[(q - 1) & 1];   // compile-time parity
            float B[4], D[4];
            ld4(B, &Rb[rm1][lj0]);
            ld4(D, &Rb[rp1][lj0]);

            float nC[4];
            srow(C, B, D, nC, p, br0);

            if (s < NSTEPS) {
                float (*Wb)[LSTR] = Sb[q & 1];
                *(float4*)&Wb[ty][lj0] = make_float4(nC[0], nC[1], nC[2], nC[3]);
                if ((t & 63) == 0)
                    __atomic_store_n(&fl[w], s, __ATOMIC_RELEASE);
            }
            C[0] = nC[0]; C[1] = nC[1]; C[2] = nC[2]; C[3] = nC[3];

            if (own) *(float4*)dst = make_float4(C[0], C[1], C[2], C[3]);
            dst += (long)PTS;
        }

        // ---- super-step boundary k = sup+1 --------------------------------
        const int k = sup + 1;
        asm volatile("s_waitcnt vmcnt(0)" ::: "memory");  // own stores in L2
        __syncthreads();
        if (t == 0) {
            __threadfence();                               // wb to coherence pt
            __atomic_store_n(&gfl[bid], k, __ATOMIC_RELEASE);
        }
        if (nbid >= 0) {                                   // lanes 0..7, wave 0
            while (__atomic_load_n(&gfl[nbid], __ATOMIC_RELAXED) < k)
                __builtin_amdgcn_s_sleep(2);
        }
        __syncthreads();                                   // spins complete
        if (t == 0) __threadfence();                       // inv L1/L2 for halo
        __syncthreads();

        // ---- re-stage from frame (16k - 1); owned tile from registers
        const float* F = outBase + (size_t)(16 * k - 1) * PTS;
        if (own) {
            *(float4*)&Sb[0][ty][lj0] = make_float4(C[0], C[1], C[2], C[3]);
        } else {
            const int gi_ = gi0 + ty;
            float tmp[4];
            #pragma unroll
            for (int e = 0; e < 4; ++e) {
                const int gj_ = gj0 + lj0 + e;
                tmp[e] = ((unsigned)gi_ < GN && (unsigned)gj_ < GN)
                         ? F[(size_t)gi_ * GN + gj_] : 0.0f;
            }
            *(float4*)&Sb[0][ty][lj0] = make_float4(tmp[0], tmp[1], tmp[2], tmp[3]);
        }
        __syncthreads();
        if (!own) ld4(C, &Sb[0][ty][lj0]);
        // fl values are all >= 16k here (set during q==16), so the next
        // super-step's q==2 wait (>= 16k+1) is consistent.
    }

    // ---- tail: steps 497..499 (halo depth 3 <= 16, freshly re-staged)
    #pragma unroll
    for (int q = 1; q <= 3; ++q) {
        const int s = NSUP * KMAX + q;                     // 497,498,499
        if (q > 1) {
            while (__atomic_load_n(&fl[wm1], __ATOMIC_ACQUIRE) < s - 1 ||
                   __atomic_load_n(&fl[wp1], __ATOMIC_ACQUIRE) < s - 1)
                __builtin_amdgcn_s_sleep(1);
        }
        const float (*Rb)[LSTR] = Sb[(q - 1) & 1];
        float B[4], D[4];
        ld4(B, &Rb[rm1][lj0]);
        ld4(D, &Rb[rp1][lj0]);
        float nC[4];
        srow(C, B, D, nC, p, br0);
        if (s < NSTEPS) {
            float (*Wb)[LSTR] = Sb[q & 1];
            *(float4*)&Wb[ty][lj0] = make_float4(nC[0], nC[1], nC[2], nC[3]);
            if ((t & 63) == 0)
                __atomic_store_n(&fl[w], s, __ATOMIC_RELEASE);
        }
        C[0] = nC[0]; C[1] = nC[1]; C[2] = nC[2]; C[3] = nC[3];
        if (own) *(float4*)dst = make_float4(C[0], C[1], C[2], C[3]);
        dst += (long)PTS;
    }
}

extern "C" void kernel_launch(void* const* d_in, const int* in_sizes, int n_in,
                              void* d_out, int out_size, void* d_ws, size_t ws_size,
                              hipStream_t stream)
{
    const float* u0 = (const float*)d_in[0];
    const float* k1 = (const float*)d_in[1];
    const float* k2 = (const float*)d_in[2];
    const float* a1 = (const float*)d_in[3];
    const float* a2 = (const float*)d_in[4];
    float* out = (float*)d_out;
    int* gfl = (int*)d_ws;

    // zero the 256 block-progress flags every call (replay-deterministic)
    hipMemsetAsync(gfl, 0, 256 * sizeof(int), stream);
    heat_pers<<<256, 1024, 0, stream>>>(u0, out, k1, k2, a1, a2, gfl);
}

// Round 12
// 337.392 us; speedup vs baseline: 2.3488x; 2.3488x over previous
//
#include <hip/hip_runtime.h>

// Heat equation, 2 materials, N=512, 499 steps, all frames written.
// Temporal tiling: K=16 steps/launch, 32 dispatches, 1024-thread blocks,
// thread = 1x4 strip (row ty, cols lj0..lj0+3) of a 64x64 halo'd region.
// R12 = R9 engine (nearest-neighbor wave sync, no block barrier in loop)
// with a shortened per-step chain:
//  - ONE ds_read_b64 mailbox poll (vs 2 acquire loads), no s_sleep
//  - NO lgkmcnt(0) release/acquire drains: pure-LDS DS ops from a wave
//    complete in order, so plain stores + compiler barriers give the
//    publish->flag and flag->read ordering
//  - each wave posts progress into both neighbors' mailboxes with a
//    single 2-active-lane ds_write_b32; edge waves use +INF sentinels.
// Global frame stores stay fully async (nothing drains vmcnt in-loop).

#define GN 512
#define NSTEPS 499
#define MBND 256
#define INV_DX2 261121.0f     // 511^2 = 1/dx^2
#define DT 5e-7f

#define TO 32                 // owned tile edge
#define KMAX 16               // steps per launch (= trapezoid margin)
#define LOAD 64               // TO + 2*KMAX
#define LSTR 68               // padded LDS row stride (floats)

// DPP shifts within 16-lane rows. Out-of-range lanes keep their own value
// (bound_ctrl=0, old=src) -> junk only at region edges, outside trapezoid.
__device__ __forceinline__ float dpp_row_shr1(float x) {  // lane i <- i-1
    int v = __builtin_amdgcn_update_dpp(__float_as_int(x), __float_as_int(x),
                                        0x111, 0xf, 0xf, false);
    return __int_as_float(v);
}
__device__ __forceinline__ float dpp_row_shl1(float x) {  // lane i <- i+1
    int v = __builtin_amdgcn_update_dpp(__float_as_int(x), __float_as_int(x),
                                        0x101, 0xf, 0xf, false);
    return __int_as_float(v);
}

struct Prm {
    float Ac[4]; bool ifc[4]; bool bcl[4];
    float k1, k2, invk;
    bool aI, aC, aR;
};

__device__ __forceinline__ void srow(const float x[4], const float up[4],
                                     const float dn[4], float out[4],
                                     const Prm& p, bool brF)
{
    const float lf = dpp_row_shr1(x[3]);
    const float rg = dpp_row_shl1(x[0]);
    const float le[4] = {lf, x[0], x[1], x[2]};
    const float ri[4] = {x[1], x[2], x[3], rg};
    #pragma unroll
    for (int j = 0; j < 4; ++j) {
        float v = fmaf(p.Ac[j], fmaf(-4.0f, x[j], (up[j] + dn[j]) + (le[j] + ri[j])), x[j]);
        if (p.aI) v = p.ifc[j] ? (p.k1 * ri[j] + p.k2 * le[j]) * p.invk : v; // OLD nbrs
        if (p.aC) v = p.bcl[j] ? 0.0f : v;
        if (p.aR) v = brF ? 0.0f : v;
        out[j] = v;
    }
}

__device__ __forceinline__ void ld4(float d[4], const float* s) {
    const float4 v = *(const float4*)s;
    d[0] = v.x; d[1] = v.y; d[2] = v.z; d[3] = v.w;
}

template<int STEPS>   // 16 (full) or 3 (tail)
__global__ __launch_bounds__(1024) void heat_multi(
    const float* __restrict__ Tin, float* __restrict__ outBase,
    const float* __restrict__ k1p, const float* __restrict__ k2p,
    const float* __restrict__ a1p, const float* __restrict__ a2p)
{
    __shared__ float Sb[2][LOAD][LSTR];
    // mbx[w+1] = wave w's mailbox: .x written by wave w-1, .y by wave w+1.
    // mbx[0], mbx[17] are write-only guards. Sentinels: wave 0 has no
    // upper neighbor -> mbx[1].x = +INF; wave 15 -> mbx[16].y = +INF.
    __shared__ int2 mbx[18];

    const int t  = threadIdx.x;              // 0..1023
    const int bi = blockIdx.x >> 4;          // 16x16 tile grid
    const int bj = blockIdx.x & 15;
    const int gi0 = bi * TO - KMAX;
    const int gj0 = bj * TO - KMAX;

    const int tx = t & 15, ty = t >> 4;      // 64 rows x 16 col-groups
    const int w  = t >> 6;                   // wave id 0..15
    const int lane = t & 63;
    const int lj0 = tx * 4;

    // ---- stage region @t0 into Sb[0]; own float4 == (ty,lj0) assignment
    float C[4];
    {
        const bool innerB = (gi0 >= 0) && (gi0 + LOAD <= GN) &&
                            (gj0 >= 0) && (gj0 + LOAD <= GN);
        float4 v;
        if (innerB) {
            v = *(const float4*)&Tin[(size_t)(gi0 + ty) * GN + (gj0 + lj0)];
        } else {
            const int gi_ = gi0 + ty;
            float tmp[4];
            #pragma unroll
            for (int e = 0; e < 4; ++e) {
                const int gj_ = gj0 + lj0 + e;
                tmp[e] = ((unsigned)gi_ < GN && (unsigned)gj_ < GN)
                         ? Tin[(size_t)gi_ * GN + gj_] : 0.0f;
            }
            v = make_float4(tmp[0], tmp[1], tmp[2], tmp[3]);
        }
        *(float4*)&Sb[0][ty][lj0] = v;
        C[0] = v.x; C[1] = v.y; C[2] = v.z; C[3] = v.w;
    }
    if (t < 18) {
        mbx[t].x = (t == 1)  ? 0x7fffffff : 0;   // "state 0 published"
        mbx[t].y = (t == 16) ? 0x7fffffff : 0;
    }
    __syncthreads();                         // the ONLY block-wide barrier

    // clamped neighbor-row indices (junk-safe: outside trapezoid)
    const int rm1 = (ty >= 1) ? ty - 1 : 0;
    const int rp1 = (ty <= LOAD - 2) ? ty + 1 : LOAD - 1;

    Prm p;
    p.k1 = k1p[0]; p.k2 = k2p[0];
    const float a1 = a1p[0], a2 = a2p[0];
    p.invk = 1.0f / (p.k1 + p.k2);
    #pragma unroll
    for (int j = 0; j < 4; ++j) {
        const int gj_ = gj0 + lj0 + j;
        p.Ac[j]  = (DT * INV_DX2) * ((gj_ < MBND) ? a1 : a2);
        p.ifc[j] = (gj_ == MBND - 1);
        p.bcl[j] = (gj_ <= 0) || (gj_ >= GN - 1);
    }
    p.aI = (bj == 7) || (bj == 8);
    p.aC = (bj == 0) || (bj == 15);
    p.aR = (bi == 0) || (bi == 15);

    const int gi = gi0 + ty;
    const bool br0 = (gi <= 0) || (gi >= GN - 1);

    const bool own = (tx >= 4) && (tx < 12) && (ty >= KMAX) && (ty < KMAX + TO);
    float* dst = outBase + ((long)gi * GN + (gj0 + lj0));

    // flag-write address for the 2 active lanes (lane0 -> lower nbr's .x,
    // lane1 -> upper nbr's .y); other lanes inactive.
    volatile int* fla = (lane == 0) ? &mbx[w + 2].x : &mbx[w].y;

    #pragma unroll
    for (int s = 1; s <= STEPS; ++s) {
        // 1) wait until both neighbor waves published state s-1
        //    (one ds_read_b64 poll; no sleep; sentinels cover edges)
        if (s > 1) {
            while (true) {
                const long long v = *(volatile long long*)&mbx[w + 1];
                if ((int)v >= s - 1 && (int)(v >> 32) >= s - 1) break;
            }
            asm volatile("" ::: "memory");   // no Sb reads hoisted above
        }
        // 2) read vertical neighbors (state s-1)
        const float (*Rb)[LSTR] = Sb[(s - 1) & 1];
        float B[4], D[4];
        ld4(B, &Rb[rm1][lj0]);
        ld4(D, &Rb[rp1][lj0]);

        // 3) compute state s for own row
        float nC[4];
        srow(C, B, D, nC, p, br0);

        // 4) publish row, then flag (same-wave DS ops complete in order;
        //    compiler barrier stops reordering — no lgkmcnt drain needed)
        if (s < STEPS) {
            float (*Wb)[LSTR] = Sb[s & 1];
            *(float4*)&Wb[ty][lj0] = make_float4(nC[0], nC[1], nC[2], nC[3]);
            asm volatile("" ::: "memory");
            if (lane < 2) *fla = s;
            asm volatile("" ::: "memory");
        }
        C[0] = nC[0]; C[1] = nC[1]; C[2] = nC[2]; C[3] = nC[3];

        // 5) stream owned strip (async; nothing in the loop drains vmcnt)
        if (own) *(float4*)dst = make_float4(C[0], C[1], C[2], C[3]);
        dst += (long)GN * GN;
    }
}

extern "C" void kernel_launch(void* const* d_in, const int* in_sizes, int n_in,
                              void* d_out, int out_size, void* d_ws, size_t ws_size,
                              hipStream_t stream)
{
    const float* u0 = (const float*)d_in[0];
    const float* k1 = (const float*)d_in[1];
    const float* k2 = (const float*)d_in[2];
    const float* a1 = (const float*)d_in[3];
    const float* a2 = (const float*)d_in[4];
    float* out = (float*)d_out;

    const int pts = GN * GN;
    const float* src = u0;
    int done = 0;
    while (done < NSTEPS) {
        int steps = NSTEPS - done;
        if (steps > KMAX) steps = KMAX;
        float* ob = out + (size_t)done * pts;
        if (steps == KMAX)
            heat_multi<KMAX><<<256, 1024, 0, stream>>>(src, ob, k1, k2, a1, a2);
        else  // NSTEPS = 31*16 + 3 -> remainder is always 3
            heat_multi<3><<<256, 1024, 0, stream>>>(src, ob, k1, k2, a1, a2);
        src = ob + (size_t)(steps - 1) * pts;
        done += steps;
    }
}